// Round 19
// baseline (301.080 us; speedup 1.0000x reference)
//
#include <hip/hip_runtime.h>
#include <stdint.h>

typedef uint16_t u16;
typedef __attribute__((ext_vector_type(8))) short bf16x8;
typedef __attribute__((ext_vector_type(4))) float f32x4;

// B=2, L=2048, D=2048, H=16, C=128
// ws layout: xb@0 wqb@16777216 wyb@41943040 qb@50331648 kb@67108864
//            vt@83886080 yb@100663296  (total 117,440,512 bytes)

__device__ __forceinline__ u16 f2bf(float f) {
  uint32_t u = __builtin_bit_cast(uint32_t, f);
  u += 0x7fffu + ((u >> 16) & 1u);
  return (u16)(u >> 16);
}
__device__ __forceinline__ float bf2f(u16 h) {
  return __builtin_bit_cast(float, (uint32_t)h << 16);
}
__device__ __forceinline__ uint32_t pack2bf(float a, float b) {
  uint32_t ua = __builtin_bit_cast(uint32_t, a) + 0x7fffu;
  uint32_t ub = __builtin_bit_cast(uint32_t, b) + 0x7fffu;
  return (ua >> 16) | (ub & 0xffff0000u);
}
__device__ __forceinline__ void gl_lds16(const u16* g, u16* l) {
  __builtin_amdgcn_global_load_lds((const __attribute__((address_space(1))) uint32_t*)g,
                                   (__attribute__((address_space(3))) uint32_t*)l, 16, 0, 0);
}

// Fused f32->bf16 cast of x, wqkv, wy in one launch.
__global__ __launch_bounds__(256) void cast3(const float* __restrict__ x,
                                             const float* __restrict__ wqkv,
                                             const float* __restrict__ wy,
                                             u16* __restrict__ xb, u16* __restrict__ wqb,
                                             u16* __restrict__ wyb) {
  const int N1 = 2097152, N2 = N1 + 3145728, N3 = N2 + 1048576;
  int stride = gridDim.x * 256;
  for (int i = blockIdx.x * 256 + threadIdx.x; i < N3; i += stride) {
    const float* src;
    u16* dst;
    int off;
    if (i < N1) {
      src = x; dst = xb; off = i;
    } else if (i < N2) {
      src = wqkv; dst = wqb; off = i - N1;
    } else {
      src = wy; dst = wyb; off = i - N2;
    }
    float4 v = *(const float4*)(src + (size_t)off * 4);
    uint32_t lo = (uint32_t)f2bf(v.x) | ((uint32_t)f2bf(v.y) << 16);
    uint32_t hi = (uint32_t)f2bf(v.z) | ((uint32_t)f2bf(v.w) << 16);
    *(uint2*)(dst + (size_t)off * 4) = make_uint2(lo, hi);
  }
}

// ---------------------------------------------------------------------------
// QKV GEMM: best-verified structure (133.2 us) — FROZEN.
// ---------------------------------------------------------------------------
__global__ __launch_bounds__(512, 1) void gemm8_qkv(
    const u16* __restrict__ A, const u16* __restrict__ Bw,
    u16* __restrict__ qb, u16* __restrict__ kb, u16* __restrict__ vt) {
  __shared__ u16 sm[57344];
  const int K = 2048;
  const int tid = threadIdx.x, lane = tid & 63;
  const int wid = tid >> 6, g = lane >> 4, lr = lane & 15;
  const int wm = wid >> 2, wn = wid & 3;
  const int m0 = blockIdx.y * 256, n0 = blockIdx.x * 192;
  const int srow = tid >> 3, sjs = (tid & 7) ^ (srow & 7);

  auto stA = [&](int buf, int kt, int R) {
    gl_lds16(A + (size_t)(m0 + R + srow) * K + kt * 64 + sjs * 8,
             &sm[buf * 28672 + R * 64 + tid * 8]);
  };
  auto stB = [&](int buf, int kt, int R) {
    gl_lds16(Bw + (size_t)(n0 + R + srow) * K + kt * 64 + sjs * 8,
             &sm[buf * 28672 + 16384 + R * 64 + tid * 8]);
  };
  auto rdA = [&](const u16* As, int mf, int ks) {
    int ra = wm * 128 + mf * 16 + lr;
    return *(const bf16x8*)&As[ra * 64 + (((ks * 4 + g) ^ (ra & 7)) * 8)];
  };
  auto rdB = [&](const u16* Bs, int nf, int ks) {
    int rb = wn * 48 + nf * 16 + lr;
    return *(const bf16x8*)&Bs[rb * 64 + (((ks * 4 + g) ^ (rb & 7)) * 8)];
  };

  f32x4 acc[8][3] = {};
  bf16x8 bc[3][2], fP0[4][2], fP1[4][2];

  stB(0, 0, 0); stB(0, 0, 64); stB(0, 0, 128);
  stA(0, 0, 0); stA(0, 0, 128);
  stA(0, 0, 64); stA(0, 0, 192);
  asm volatile("s_waitcnt vmcnt(2)" ::: "memory");
  __builtin_amdgcn_s_barrier();
  {
    const u16* As0 = &sm[0];
#pragma unroll
    for (int i = 0; i < 4; ++i)
#pragma unroll
      for (int ks = 0; ks < 2; ++ks) fP0[i][ks] = rdA(As0, i, ks);
  }

  for (int t = 0; t < 32; ++t) {
    const int cur = t & 1, nxt = cur ^ 1;
    const int kn = (t < 31) ? t + 1 : 31;
    const u16* Asc = &sm[cur * 28672];
    const u16* Bsc = &sm[cur * 28672 + 16384];
    const u16* Asn = &sm[nxt * 28672];

    stB(nxt, kn, 0); stB(nxt, kn, 64); stB(nxt, kn, 128);
    stA(nxt, kn, 0); stA(nxt, kn, 128);
    asm volatile("s_waitcnt vmcnt(5)" ::: "memory");
    __builtin_amdgcn_s_barrier();
#pragma unroll
    for (int nf = 0; nf < 3; ++nf)
#pragma unroll
      for (int ks = 0; ks < 2; ++ks) bc[nf][ks] = rdB(Bsc, nf, ks);
#pragma unroll
    for (int i = 0; i < 4; ++i)
#pragma unroll
      for (int ks = 0; ks < 2; ++ks) fP1[i][ks] = rdA(Asc, 4 + i, ks);
    __builtin_amdgcn_s_setprio(1);
#pragma unroll
    for (int i = 0; i < 4; ++i)
#pragma unroll
      for (int nf = 0; nf < 3; ++nf) {
        acc[i][nf] = __builtin_amdgcn_mfma_f32_16x16x32_bf16(
            fP0[i][0], bc[nf][0], acc[i][nf], 0, 0, 0);
        acc[i][nf] = __builtin_amdgcn_mfma_f32_16x16x32_bf16(
            fP0[i][1], bc[nf][1], acc[i][nf], 0, 0, 0);
      }
    __builtin_amdgcn_s_setprio(0);

    stA(nxt, kn, 64); stA(nxt, kn, 192);
    asm volatile("s_waitcnt vmcnt(2)" ::: "memory");
    __builtin_amdgcn_s_barrier();
#pragma unroll
    for (int i = 0; i < 4; ++i)
#pragma unroll
      for (int ks = 0; ks < 2; ++ks) fP0[i][ks] = rdA(Asn, i, ks);
    __builtin_amdgcn_s_setprio(1);
#pragma unroll
    for (int i = 0; i < 4; ++i)
#pragma unroll
      for (int nf = 0; nf < 3; ++nf) {
        acc[4 + i][nf] = __builtin_amdgcn_mfma_f32_16x16x32_bf16(
            fP1[i][0], bc[nf][0], acc[4 + i][nf], 0, 0, 0);
        acc[4 + i][nf] = __builtin_amdgcn_mfma_f32_16x16x32_bf16(
            fP1[i][1], bc[nf][1], acc[4 + i][nf], 0, 0, 0);
      }
    __builtin_amdgcn_s_setprio(0);
  }
  asm volatile("s_waitcnt vmcnt(0)" ::: "memory");

#pragma unroll
  for (int mf = 0; mf < 8; ++mf)
#pragma unroll
    for (int nf = 0; nf < 3; ++nf) {
      int n = n0 + wn * 48 + nf * 16 + lr;
      int s = n >> 11, h = (n >> 7) & 15, cb = n & 127;
#pragma unroll
      for (int r = 0; r < 4; ++r) {
        int m = m0 + wm * 128 + mf * 16 + g * 4 + r;
        int b = m >> 11, lp = m & 2047;
        u16 val = f2bf(acc[mf][nf][r]);
        if (s == 0)
          qb[(size_t)((b * 16 + h) * 2048 + lp) * 128 + cb] = val;
        else if (s == 1)
          kb[(size_t)((b * 16 + h) * 2048 + lp) * 128 + cb] = val;
        else
          vt[(size_t)((b * 16 + h) * 128 + cb) * 2048 + lp] = val;
      }
    }
}

// ---------------------------------------------------------------------------
// Output projection: 128x128, 4 waves, LDS 64KB -> 2 blocks/CU (R14-verified).
// ---------------------------------------------------------------------------
__global__ __launch_bounds__(256, 2) void gemm_out(
    const u16* __restrict__ A, const u16* __restrict__ Bw,
    float* __restrict__ out, const float* __restrict__ bias) {
  __shared__ u16 sm[32768];
  const int K = 2048;
  const int tid = threadIdx.x, lane = tid & 63;
  const int wn = tid >> 6, g = lane >> 4, lr = lane & 15;
  const int m0 = blockIdx.y * 128, n0 = blockIdx.x * 128;
  const int srow = tid >> 3, sjs = (tid & 7) ^ (srow & 7);

  auto stA = [&](int buf, int kt, int R) {
    gl_lds16(A + (size_t)(m0 + R + srow) * K + kt * 64 + sjs * 8,
             &sm[buf * 16384 + R * 64 + tid * 8]);
  };
  auto stB = [&](int buf, int kt, int R) {
    gl_lds16(Bw + (size_t)(n0 + R + srow) * K + kt * 64 + sjs * 8,
             &sm[buf * 16384 + 8192 + R * 64 + tid * 8]);
  };
  auto rdA = [&](const u16* As, int mf, int ks) {
    int ra = mf * 16 + lr;
    return *(const bf16x8*)&As[ra * 64 + (((ks * 4 + g) ^ (ra & 7)) * 8)];
  };
  auto rdB = [&](const u16* Bs, int nf, int ks) {
    int rb = wn * 32 + nf * 16 + lr;
    return *(const bf16x8*)&Bs[rb * 64 + (((ks * 4 + g) ^ (rb & 7)) * 8)];
  };

  f32x4 acc[8][2] = {};
  bf16x8 bc[2][2], fP0[4][2], fP1[4][2];

  stB(0, 0, 0); stB(0, 0, 32); stB(0, 0, 64); stB(0, 0, 96);
  stA(0, 0, 0); stA(0, 0, 32);
  stA(0, 0, 64); stA(0, 0, 96);
  asm volatile("s_waitcnt vmcnt(2)" ::: "memory");
  __builtin_amdgcn_s_barrier();
  {
    const u16* As0 = &sm[0];
#pragma unroll
    for (int i = 0; i < 4; ++i)
#pragma unroll
      for (int ks = 0; ks < 2; ++ks) fP0[i][ks] = rdA(As0, i, ks);
  }

  for (int t = 0; t < 32; ++t) {
    const int cur = t & 1, nxt = cur ^ 1;
    const int kn = (t < 31) ? t + 1 : 31;
    const u16* Asc = &sm[cur * 16384];
    const u16* Bsc = &sm[cur * 16384 + 8192];
    const u16* Asn = &sm[nxt * 16384];

    // ---- P0 ----
    stB(nxt, kn, 0); stB(nxt, kn, 32); stB(nxt, kn, 64); stB(nxt, kn, 96);
    stA(nxt, kn, 0); stA(nxt, kn, 32);
    asm volatile("s_waitcnt vmcnt(6)" ::: "memory");
    __builtin_amdgcn_s_barrier();
#pragma unroll
    for (int nf = 0; nf < 2; ++nf)
#pragma unroll
      for (int ks = 0; ks < 2; ++ks) bc[nf][ks] = rdB(Bsc, nf, ks);
#pragma unroll
    for (int i = 0; i < 4; ++i)
#pragma unroll
      for (int ks = 0; ks < 2; ++ks) fP1[i][ks] = rdA(Asc, 4 + i, ks);
    __builtin_amdgcn_s_setprio(1);
#pragma unroll
    for (int i = 0; i < 4; ++i)
#pragma unroll
      for (int nf = 0; nf < 2; ++nf) {
        acc[i][nf] = __builtin_amdgcn_mfma_f32_16x16x32_bf16(
            fP0[i][0], bc[nf][0], acc[i][nf], 0, 0, 0);
        acc[i][nf] = __builtin_amdgcn_mfma_f32_16x16x32_bf16(
            fP0[i][1], bc[nf][1], acc[i][nf], 0, 0, 0);
      }
    __builtin_amdgcn_s_setprio(0);

    // ---- P1 ----
    stA(nxt, kn, 64); stA(nxt, kn, 96);
    asm volatile("s_waitcnt vmcnt(2)" ::: "memory");
    __builtin_amdgcn_s_barrier();
#pragma unroll
    for (int i = 0; i < 4; ++i)
#pragma unroll
      for (int ks = 0; ks < 2; ++ks) fP0[i][ks] = rdA(Asn, i, ks);
    __builtin_amdgcn_s_setprio(1);
#pragma unroll
    for (int i = 0; i < 4; ++i)
#pragma unroll
      for (int nf = 0; nf < 2; ++nf) {
        acc[4 + i][nf] = __builtin_amdgcn_mfma_f32_16x16x32_bf16(
            fP1[i][0], bc[nf][0], acc[4 + i][nf], 0, 0, 0);
        acc[4 + i][nf] = __builtin_amdgcn_mfma_f32_16x16x32_bf16(
            fP1[i][1], bc[nf][1], acc[4 + i][nf], 0, 0, 0);
      }
    __builtin_amdgcn_s_setprio(0);
  }
  asm volatile("s_waitcnt vmcnt(0)" ::: "memory");

#pragma unroll
  for (int mf = 0; mf < 8; ++mf)
#pragma unroll
    for (int nf = 0; nf < 2; ++nf) {
      int n = n0 + wn * 32 + nf * 16 + lr;
      float bv = bias[n];
#pragma unroll
      for (int r = 0; r < 4; ++r) {
        int m = m0 + mf * 16 + g * 4 + r;
        out[(size_t)m * 2048 + n] = acc[mf][nf][r] + bv;
      }
    }
}

// In-place RMSNorm + RoPE on K only (Q is fused into attn_k's prologue).
__global__ __launch_bounds__(256) void k_fix(u16* __restrict__ kb,
                                             const float* __restrict__ theta) {
  const int row = blockIdx.x * 4 + (threadIdx.x >> 6);
  const int lane = threadIdx.x & 63;
  const int bh = row >> 11, l = row & 2047;
  const int b = bh >> 4, h = bh & 15;
  float th = theta[(size_t)(b * 2048 + l) * 1024 + h * 64 + lane];
  float sn, cs;
  __sincosf(th, &sn, &cs);
  uint32_t* p = (uint32_t*)(kb + (size_t)row * 128) + lane;
  uint32_t v = *p;
  float x0 = bf2f((u16)(v & 0xffff)), x1 = bf2f((u16)(v >> 16));
  float ss = x0 * x0 + x1 * x1;
#pragma unroll
  for (int m = 1; m <= 32; m <<= 1) ss += __shfl_xor(ss, m);
  float rn = rsqrtf(ss * (1.0f / 128.0f) + 1e-5f);
  x0 *= rn;
  x1 *= rn;
  float y0 = x0 * cs - x1 * sn;
  float y1 = x0 * sn + x1 * cs;
  *p = (uint32_t)f2bf(y0) | ((uint32_t)f2bf(y1) << 16);
}

// Flash attention fwd v5: same verified triple-buffer counted-vmcnt sync as
// R11/R18, re-parameterized for 2 blocks/CU: 16 q-rows/wave (qs dim removed),
// qtile in [0,16), grid 512 = 8 XCD x 4 bh x 16 qtiles, launch_bounds(512,2)
// -> 4 waves/SIMD to hide softmax VALU + barrier lockstep under the matrix
// pipe (m114 cross-wave overlap). LDS 48KB x 2 = 96KB/CU; KV per XCD still
// exactly its 4MB L2. Q RMSNorm+RoPE fused at load (R18-verified).
__global__ __launch_bounds__(512, 2) void attn_k(const u16* __restrict__ qb,
                                                 const u16* __restrict__ kb,
                                                 const u16* __restrict__ vt,
                                                 const float* __restrict__ theta,
                                                 u16* __restrict__ yb) {
  __shared__ u16 sm[49152];  // K [3][64][128] @0, V [3][128][64] @24576 elems
  const int gid = blockIdx.x;
  const int bh = (gid & 7) * 4 + ((gid >> 3) & 3);
  const int qtile = gid >> 5;  // [0,16)
  const int b = bh >> 4, h = bh & 15;
  const int tid = threadIdx.x, lane = tid & 63, wid = tid >> 6;
  const int g = lane >> 4, lr = lane & 15;
  const int q0 = qtile * 128 + wid * 16;

  bf16x8 qf[4];
  {
    const int l = q0 + lr;
    const u16* qrow = qb + (size_t)(bh * 2048 + l) * 128;
    float ss = 0.f;
#pragma unroll
    for (int ks = 0; ks < 4; ++ks) {
      bf16x8 raw = *(const bf16x8*)&qrow[ks * 32 + g * 8];
#pragma unroll
      for (int e = 0; e < 8; ++e) {
        float xv = bf2f((u16)raw[e]);
        ss += xv * xv;
      }
    }
    ss += __shfl_xor(ss, 16);
    ss += __shfl_xor(ss, 32);
    float rn = rsqrtf(ss * (1.0f / 128.0f) + 1e-5f) * 0.12751743f;  // *log2e/sqrt(128)
    const float* thp = theta + (size_t)(b * 2048 + l) * 1024 + h * 64;
#pragma unroll
    for (int ks = 0; ks < 4; ++ks) {
      bf16x8 raw = *(const bf16x8*)&qrow[ks * 32 + g * 8];
      float4 th4 = *(const float4*)&thp[ks * 16 + g * 4];
      union {
        uint32_t u[4];
        bf16x8 v;
      } outv;
#pragma unroll
      for (int j = 0; j < 4; ++j) {
        float th = (&th4.x)[j];
        float sn, cs;
        __sincosf(th, &sn, &cs);
        float x0 = bf2f((u16)raw[2 * j]) * rn;
        float x1 = bf2f((u16)raw[2 * j + 1]) * rn;
        outv.u[j] = pack2bf(x0 * cs - x1 * sn, x0 * sn + x1 * cs);
      }
      qf[ks] = outv.v;
    }
  }

  auto stage = [&](int buf, int kv) {
#pragma unroll
    for (int i = 0; i < 2; ++i) {  // K tile 64x128
      int ci = i * 512 + tid;
      int row = ci >> 4, j = ci & 15;
      gl_lds16(kb + (size_t)(bh * 2048 + kv + row) * 128 + (j ^ (row & 7)) * 8,
               &sm[buf * 8192 + ci * 8]);
    }
#pragma unroll
    for (int i = 0; i < 2; ++i) {  // V tile 128x64
      int ci = i * 512 + tid;
      int row = ci >> 3, j = ci & 7;
      gl_lds16(vt + (size_t)(bh * 128 + row) * 2048 + kv + (j ^ (row & 7)) * 8,
               &sm[24576 + buf * 8192 + ci * 8]);
    }
  };

  f32x4 acc[8] = {};
  float mrun = -1e30f, lrun = 0.f;
  const int sA = (2 * (g & 1)) * 16 + lr, sB = sA + 16;
  const bool hi2 = (g >> 1) != 0;

  stage(0, 0);
  stage(1, 64);
  asm volatile("s_waitcnt vmcnt(4)" ::: "memory");
  __builtin_amdgcn_s_barrier();

  int cur = 0;
  for (int t = 0; t < 32; ++t) {
    if (t < 31) {
      int nb = (cur == 0) ? 2 : cur - 1;           // (t+2)%3
      int kvn = ((t < 30) ? t + 2 : 31) * 64;
      stage(nb, kvn);
    }
    const u16* Ks = &sm[cur * 8192];
    const u16* Vs = &sm[24576 + cur * 8192];

    f32x4 st[4] = {};
#pragma unroll
    for (int ks = 0; ks < 4; ++ks) {
      bf16x8 kf[4];
#pragma unroll
      for (int kt = 0; kt < 4; ++kt) {
        int row = kt * 16 + lr;
        kf[kt] = *(const bf16x8*)&Ks[row * 128 + (((ks * 4 + g) ^ (row & 7)) * 8)];
      }
#pragma unroll
      for (int kt = 0; kt < 4; ++kt)
        st[kt] = __builtin_amdgcn_mfma_f32_16x16x32_bf16(kf[kt], qf[ks], st[kt], 0, 0, 0);
    }

    float m01 = fmaxf(fmaxf(st[0][0], st[0][1]), fmaxf(st[0][2], st[0][3]));
    float m23 = fmaxf(fmaxf(st[1][0], st[1][1]), fmaxf(st[1][2], st[1][3]));
    float m45 = fmaxf(fmaxf(st[2][0], st[2][1]), fmaxf(st[2][2], st[2][3]));
    float m67 = fmaxf(fmaxf(st[3][0], st[3][1]), fmaxf(st[3][2], st[3][3]));
    float pmax = fmaxf(fmaxf(m01, m23), fmaxf(m45, m67));
    pmax = fmaxf(pmax, __shfl_xor(pmax, 16));
    pmax = fmaxf(pmax, __shfl_xor(pmax, 32));
    if (!__all(pmax - mrun <= 8.0f)) {  // defer-max (T13)
      float mnew = fmaxf(mrun, pmax);
      float corr = __builtin_amdgcn_exp2f(mrun - mnew);
      lrun *= corr;
      mrun = mnew;
#pragma unroll
      for (int ct = 0; ct < 8; ++ct) {
        acc[ct][0] *= corr;
        acc[ct][1] *= corr;
        acc[ct][2] *= corr;
        acc[ct][3] *= corr;
      }
    }
    uint32_t pw[4][2];
    float rsum = 0.f;
#pragma unroll
    for (int kt = 0; kt < 4; ++kt)
#pragma unroll
      for (int hf = 0; hf < 2; ++hf) {
        float e0 = __builtin_amdgcn_exp2f(st[kt][2 * hf] - mrun);
        float e1 = __builtin_amdgcn_exp2f(st[kt][2 * hf + 1] - mrun);
        rsum += e0 + e1;
        pw[kt][hf] = pack2bf(e0, e1);
      }
    rsum += __shfl_xor(rsum, 16);
    rsum += __shfl_xor(rsum, 32);
    lrun += rsum;

#pragma unroll
    for (int ks2 = 0; ks2 < 2; ++ks2) {
      uint32_t a0 = __shfl(pw[ks2 * 2][0], sA);
      uint32_t a1 = __shfl(pw[ks2 * 2][1], sA);
      uint32_t a2 = __shfl(pw[ks2 * 2][0], sB);
      uint32_t a3 = __shfl(pw[ks2 * 2][1], sB);
      uint32_t b0 = __shfl(pw[ks2 * 2 + 1][0], sA);
      uint32_t b1 = __shfl(pw[ks2 * 2 + 1][1], sA);
      uint32_t b2 = __shfl(pw[ks2 * 2 + 1][0], sB);
      uint32_t b3 = __shfl(pw[ks2 * 2 + 1][1], sB);
      union {
        uint32_t u[4];
        bf16x8 v;
      } tt;
      tt.u[0] = hi2 ? b0 : a0;
      tt.u[1] = hi2 ? b1 : a1;
      tt.u[2] = hi2 ? b2 : a2;
      tt.u[3] = hi2 ? b3 : a3;
#pragma unroll
      for (int ct = 0; ct < 8; ++ct) {
        int row = ct * 16 + lr;
        bf16x8 vf = *(const bf16x8*)&Vs[row * 64 + (((ks2 * 4 + g) ^ (row & 7)) * 8)];
        acc[ct] = __builtin_amdgcn_mfma_f32_16x16x32_bf16(vf, tt.v, acc[ct], 0, 0, 0);
      }
    }
    if (t < 31) {
      asm volatile("s_waitcnt vmcnt(4)" ::: "memory");
      __builtin_amdgcn_s_barrier();
    }
    cur = (cur == 2) ? 0 : cur + 1;
  }
  asm volatile("s_waitcnt vmcnt(0)" ::: "memory");

  {
    float inv = 1.f / lrun;
    const size_t orow = (size_t)(b * 2048 + q0 + lr) * 2048 + h * 128;
#pragma unroll
    for (int ct = 0; ct < 8; ++ct) {
      uint32_t lo = pack2bf(acc[ct][0] * inv, acc[ct][1] * inv);
      uint32_t hi = pack2bf(acc[ct][2] * inv, acc[ct][3] * inv);
      *(uint2*)&yb[orow + ct * 16 + g * 4] = make_uint2(lo, hi);
    }
  }
}

extern "C" void kernel_launch(void* const* d_in, const int* in_sizes, int n_in,
                              void* d_out, int out_size, void* d_ws, size_t ws_size,
                              hipStream_t stream) {
  const float* x = (const float*)d_in[0];
  const float* theta = (const float*)d_in[1];
  const float* wqkv = (const float*)d_in[2];
  const float* wy = (const float*)d_in[3];
  const float* by = (const float*)d_in[4];
  float* out = (float*)d_out;
  char* ws = (char*)d_ws;
  u16* xb  = (u16*)(ws + 0);
  u16* wqb = (u16*)(ws + 16777216);
  u16* wyb = (u16*)(ws + 41943040);
  u16* qb  = (u16*)(ws + 50331648);
  u16* kb  = (u16*)(ws + 67108864);
  u16* vt  = (u16*)(ws + 83886080);
  u16* yb  = (u16*)(ws + 100663296);

  cast3<<<2048, 256, 0, stream>>>(x, wqkv, wy, xb, wqb, wyb);
  gemm8_qkv<<<dim3(32, 16), 512, 0, stream>>>(xb, wqb, qb, kb, vt);
  k_fix<<<16384, 256, 0, stream>>>(kb, theta);
  attn_k<<<512, 512, 0, stream>>>(qb, kb, vt, theta, yb);
  gemm_out<<<dim3(16, 32), 256, 0, stream>>>(yb, wyb, out, by);
}

// Round 21
// 280.465 us; speedup vs baseline: 1.0735x; 1.0735x over previous
//
#include <hip/hip_runtime.h>
#include <stdint.h>

typedef uint16_t u16;
typedef __attribute__((ext_vector_type(8))) short bf16x8;
typedef __attribute__((ext_vector_type(4))) float f32x4;

// B=2, L=2048, D=2048, H=16, C=128
// ws layout: xb@0 wqb@16777216 wyb@41943040 qb@50331648 kb@67108864
//            vt@83886080 yb@100663296  (total 117,440,512 bytes)

__device__ __forceinline__ u16 f2bf(float f) {
  uint32_t u = __builtin_bit_cast(uint32_t, f);
  u += 0x7fffu + ((u >> 16) & 1u);
  return (u16)(u >> 16);
}
__device__ __forceinline__ float bf2f(u16 h) {
  return __builtin_bit_cast(float, (uint32_t)h << 16);
}
__device__ __forceinline__ uint32_t pack2bf(float a, float b) {
  uint32_t ua = __builtin_bit_cast(uint32_t, a) + 0x7fffu;
  uint32_t ub = __builtin_bit_cast(uint32_t, b) + 0x7fffu;
  return (ua >> 16) | (ub & 0xffff0000u);
}
__device__ __forceinline__ void gl_lds16(const u16* g, u16* l) {
  __builtin_amdgcn_global_load_lds((const __attribute__((address_space(1))) uint32_t*)g,
                                   (__attribute__((address_space(3))) uint32_t*)l, 16, 0, 0);
}

// Fused f32->bf16 cast of x, wqkv, wy in one launch.
__global__ __launch_bounds__(256) void cast3(const float* __restrict__ x,
                                             const float* __restrict__ wqkv,
                                             const float* __restrict__ wy,
                                             u16* __restrict__ xb, u16* __restrict__ wqb,
                                             u16* __restrict__ wyb) {
  const int N1 = 2097152, N2 = N1 + 3145728, N3 = N2 + 1048576;
  int stride = gridDim.x * 256;
  for (int i = blockIdx.x * 256 + threadIdx.x; i < N3; i += stride) {
    const float* src;
    u16* dst;
    int off;
    if (i < N1) {
      src = x; dst = xb; off = i;
    } else if (i < N2) {
      src = wqkv; dst = wqb; off = i - N1;
    } else {
      src = wy; dst = wyb; off = i - N2;
    }
    float4 v = *(const float4*)(src + (size_t)off * 4);
    uint32_t lo = (uint32_t)f2bf(v.x) | ((uint32_t)f2bf(v.y) << 16);
    uint32_t hi = (uint32_t)f2bf(v.z) | ((uint32_t)f2bf(v.w) << 16);
    *(uint2*)(dst + (size_t)off * 4) = make_uint2(lo, hi);
  }
}

// ---------------------------------------------------------------------------
// QKV GEMM: best-verified structure (133.2 us) — FROZEN.
// ---------------------------------------------------------------------------
__global__ __launch_bounds__(512, 1) void gemm8_qkv(
    const u16* __restrict__ A, const u16* __restrict__ Bw,
    u16* __restrict__ qb, u16* __restrict__ kb, u16* __restrict__ vt) {
  __shared__ u16 sm[57344];
  const int K = 2048;
  const int tid = threadIdx.x, lane = tid & 63;
  const int wid = tid >> 6, g = lane >> 4, lr = lane & 15;
  const int wm = wid >> 2, wn = wid & 3;
  const int m0 = blockIdx.y * 256, n0 = blockIdx.x * 192;
  const int srow = tid >> 3, sjs = (tid & 7) ^ (srow & 7);

  auto stA = [&](int buf, int kt, int R) {
    gl_lds16(A + (size_t)(m0 + R + srow) * K + kt * 64 + sjs * 8,
             &sm[buf * 28672 + R * 64 + tid * 8]);
  };
  auto stB = [&](int buf, int kt, int R) {
    gl_lds16(Bw + (size_t)(n0 + R + srow) * K + kt * 64 + sjs * 8,
             &sm[buf * 28672 + 16384 + R * 64 + tid * 8]);
  };
  auto rdA = [&](const u16* As, int mf, int ks) {
    int ra = wm * 128 + mf * 16 + lr;
    return *(const bf16x8*)&As[ra * 64 + (((ks * 4 + g) ^ (ra & 7)) * 8)];
  };
  auto rdB = [&](const u16* Bs, int nf, int ks) {
    int rb = wn * 48 + nf * 16 + lr;
    return *(const bf16x8*)&Bs[rb * 64 + (((ks * 4 + g) ^ (rb & 7)) * 8)];
  };

  f32x4 acc[8][3] = {};
  bf16x8 bc[3][2], fP0[4][2], fP1[4][2];

  stB(0, 0, 0); stB(0, 0, 64); stB(0, 0, 128);
  stA(0, 0, 0); stA(0, 0, 128);
  stA(0, 0, 64); stA(0, 0, 192);
  asm volatile("s_waitcnt vmcnt(2)" ::: "memory");
  __builtin_amdgcn_s_barrier();
  {
    const u16* As0 = &sm[0];
#pragma unroll
    for (int i = 0; i < 4; ++i)
#pragma unroll
      for (int ks = 0; ks < 2; ++ks) fP0[i][ks] = rdA(As0, i, ks);
  }

  for (int t = 0; t < 32; ++t) {
    const int cur = t & 1, nxt = cur ^ 1;
    const int kn = (t < 31) ? t + 1 : 31;
    const u16* Asc = &sm[cur * 28672];
    const u16* Bsc = &sm[cur * 28672 + 16384];
    const u16* Asn = &sm[nxt * 28672];

    stB(nxt, kn, 0); stB(nxt, kn, 64); stB(nxt, kn, 128);
    stA(nxt, kn, 0); stA(nxt, kn, 128);
    asm volatile("s_waitcnt vmcnt(5)" ::: "memory");
    __builtin_amdgcn_s_barrier();
#pragma unroll
    for (int nf = 0; nf < 3; ++nf)
#pragma unroll
      for (int ks = 0; ks < 2; ++ks) bc[nf][ks] = rdB(Bsc, nf, ks);
#pragma unroll
    for (int i = 0; i < 4; ++i)
#pragma unroll
      for (int ks = 0; ks < 2; ++ks) fP1[i][ks] = rdA(Asc, 4 + i, ks);
    __builtin_amdgcn_s_setprio(1);
#pragma unroll
    for (int i = 0; i < 4; ++i)
#pragma unroll
      for (int nf = 0; nf < 3; ++nf) {
        acc[i][nf] = __builtin_amdgcn_mfma_f32_16x16x32_bf16(
            fP0[i][0], bc[nf][0], acc[i][nf], 0, 0, 0);
        acc[i][nf] = __builtin_amdgcn_mfma_f32_16x16x32_bf16(
            fP0[i][1], bc[nf][1], acc[i][nf], 0, 0, 0);
      }
    __builtin_amdgcn_s_setprio(0);

    stA(nxt, kn, 64); stA(nxt, kn, 192);
    asm volatile("s_waitcnt vmcnt(2)" ::: "memory");
    __builtin_amdgcn_s_barrier();
#pragma unroll
    for (int i = 0; i < 4; ++i)
#pragma unroll
      for (int ks = 0; ks < 2; ++ks) fP0[i][ks] = rdA(Asn, i, ks);
    __builtin_amdgcn_s_setprio(1);
#pragma unroll
    for (int i = 0; i < 4; ++i)
#pragma unroll
      for (int nf = 0; nf < 3; ++nf) {
        acc[4 + i][nf] = __builtin_amdgcn_mfma_f32_16x16x32_bf16(
            fP1[i][0], bc[nf][0], acc[4 + i][nf], 0, 0, 0);
        acc[4 + i][nf] = __builtin_amdgcn_mfma_f32_16x16x32_bf16(
            fP1[i][1], bc[nf][1], acc[4 + i][nf], 0, 0, 0);
      }
    __builtin_amdgcn_s_setprio(0);
  }
  asm volatile("s_waitcnt vmcnt(0)" ::: "memory");

#pragma unroll
  for (int mf = 0; mf < 8; ++mf)
#pragma unroll
    for (int nf = 0; nf < 3; ++nf) {
      int n = n0 + wn * 48 + nf * 16 + lr;
      int s = n >> 11, h = (n >> 7) & 15, cb = n & 127;
#pragma unroll
      for (int r = 0; r < 4; ++r) {
        int m = m0 + wm * 128 + mf * 16 + g * 4 + r;
        int b = m >> 11, lp = m & 2047;
        u16 val = f2bf(acc[mf][nf][r]);
        if (s == 0)
          qb[(size_t)((b * 16 + h) * 2048 + lp) * 128 + cb] = val;
        else if (s == 1)
          kb[(size_t)((b * 16 + h) * 2048 + lp) * 128 + cb] = val;
        else
          vt[(size_t)((b * 16 + h) * 128 + cb) * 2048 + lp] = val;
      }
    }
}

// ---------------------------------------------------------------------------
// Output projection: 128x128, 4 waves, LDS 64KB -> 2 blocks/CU (R14-verified).
// ---------------------------------------------------------------------------
__global__ __launch_bounds__(256, 2) void gemm_out(
    const u16* __restrict__ A, const u16* __restrict__ Bw,
    float* __restrict__ out, const float* __restrict__ bias) {
  __shared__ u16 sm[32768];
  const int K = 2048;
  const int tid = threadIdx.x, lane = tid & 63;
  const int wn = tid >> 6, g = lane >> 4, lr = lane & 15;
  const int m0 = blockIdx.y * 128, n0 = blockIdx.x * 128;
  const int srow = tid >> 3, sjs = (tid & 7) ^ (srow & 7);

  auto stA = [&](int buf, int kt, int R) {
    gl_lds16(A + (size_t)(m0 + R + srow) * K + kt * 64 + sjs * 8,
             &sm[buf * 16384 + R * 64 + tid * 8]);
  };
  auto stB = [&](int buf, int kt, int R) {
    gl_lds16(Bw + (size_t)(n0 + R + srow) * K + kt * 64 + sjs * 8,
             &sm[buf * 16384 + 8192 + R * 64 + tid * 8]);
  };
  auto rdA = [&](const u16* As, int mf, int ks) {
    int ra = mf * 16 + lr;
    return *(const bf16x8*)&As[ra * 64 + (((ks * 4 + g) ^ (ra & 7)) * 8)];
  };
  auto rdB = [&](const u16* Bs, int nf, int ks) {
    int rb = wn * 32 + nf * 16 + lr;
    return *(const bf16x8*)&Bs[rb * 64 + (((ks * 4 + g) ^ (rb & 7)) * 8)];
  };

  f32x4 acc[8][2] = {};
  bf16x8 bc[2][2], fP0[4][2], fP1[4][2];

  stB(0, 0, 0); stB(0, 0, 32); stB(0, 0, 64); stB(0, 0, 96);
  stA(0, 0, 0); stA(0, 0, 32);
  stA(0, 0, 64); stA(0, 0, 96);
  asm volatile("s_waitcnt vmcnt(2)" ::: "memory");
  __builtin_amdgcn_s_barrier();
  {
    const u16* As0 = &sm[0];
#pragma unroll
    for (int i = 0; i < 4; ++i)
#pragma unroll
      for (int ks = 0; ks < 2; ++ks) fP0[i][ks] = rdA(As0, i, ks);
  }

  for (int t = 0; t < 32; ++t) {
    const int cur = t & 1, nxt = cur ^ 1;
    const int kn = (t < 31) ? t + 1 : 31;
    const u16* Asc = &sm[cur * 16384];
    const u16* Bsc = &sm[cur * 16384 + 8192];
    const u16* Asn = &sm[nxt * 16384];

    // ---- P0 ----
    stB(nxt, kn, 0); stB(nxt, kn, 32); stB(nxt, kn, 64); stB(nxt, kn, 96);
    stA(nxt, kn, 0); stA(nxt, kn, 32);
    asm volatile("s_waitcnt vmcnt(6)" ::: "memory");
    __builtin_amdgcn_s_barrier();
#pragma unroll
    for (int nf = 0; nf < 2; ++nf)
#pragma unroll
      for (int ks = 0; ks < 2; ++ks) bc[nf][ks] = rdB(Bsc, nf, ks);
#pragma unroll
    for (int i = 0; i < 4; ++i)
#pragma unroll
      for (int ks = 0; ks < 2; ++ks) fP1[i][ks] = rdA(Asc, 4 + i, ks);
    __builtin_amdgcn_s_setprio(1);
#pragma unroll
    for (int i = 0; i < 4; ++i)
#pragma unroll
      for (int nf = 0; nf < 2; ++nf) {
        acc[i][nf] = __builtin_amdgcn_mfma_f32_16x16x32_bf16(
            fP0[i][0], bc[nf][0], acc[i][nf], 0, 0, 0);
        acc[i][nf] = __builtin_amdgcn_mfma_f32_16x16x32_bf16(
            fP0[i][1], bc[nf][1], acc[i][nf], 0, 0, 0);
      }
    __builtin_amdgcn_s_setprio(0);

    // ---- P1 ----
    stA(nxt, kn, 64); stA(nxt, kn, 96);
    asm volatile("s_waitcnt vmcnt(2)" ::: "memory");
    __builtin_amdgcn_s_barrier();
#pragma unroll
    for (int i = 0; i < 4; ++i)
#pragma unroll
      for (int ks = 0; ks < 2; ++ks) fP0[i][ks] = rdA(Asn, i, ks);
    __builtin_amdgcn_s_setprio(1);
#pragma unroll
    for (int i = 0; i < 4; ++i)
#pragma unroll
      for (int nf = 0; nf < 2; ++nf) {
        acc[4 + i][nf] = __builtin_amdgcn_mfma_f32_16x16x32_bf16(
            fP1[i][0], bc[nf][0], acc[4 + i][nf], 0, 0, 0);
        acc[4 + i][nf] = __builtin_amdgcn_mfma_f32_16x16x32_bf16(
            fP1[i][1], bc[nf][1], acc[4 + i][nf], 0, 0, 0);
      }
    __builtin_amdgcn_s_setprio(0);
  }
  asm volatile("s_waitcnt vmcnt(0)" ::: "memory");

#pragma unroll
  for (int mf = 0; mf < 8; ++mf)
#pragma unroll
    for (int nf = 0; nf < 2; ++nf) {
      int n = n0 + wn * 32 + nf * 16 + lr;
      float bv = bias[n];
#pragma unroll
      for (int r = 0; r < 4; ++r) {
        int m = m0 + mf * 16 + g * 4 + r;
        out[(size_t)m * 2048 + n] = acc[mf][nf][r] + bv;
      }
    }
}

// In-place RMSNorm + RoPE on K only (Q is fused into attn_k's prologue).
__global__ __launch_bounds__(256) void k_fix(u16* __restrict__ kb,
                                             const float* __restrict__ theta) {
  const int row = blockIdx.x * 4 + (threadIdx.x >> 6);
  const int lane = threadIdx.x & 63;
  const int bh = row >> 11, l = row & 2047;
  const int b = bh >> 4, h = bh & 15;
  float th = theta[(size_t)(b * 2048 + l) * 1024 + h * 64 + lane];
  float sn, cs;
  __sincosf(th, &sn, &cs);
  uint32_t* p = (uint32_t*)(kb + (size_t)row * 128) + lane;
  uint32_t v = *p;
  float x0 = bf2f((u16)(v & 0xffff)), x1 = bf2f((u16)(v >> 16));
  float ss = x0 * x0 + x1 * x1;
#pragma unroll
  for (int m = 1; m <= 32; m <<= 1) ss += __shfl_xor(ss, m);
  float rn = rsqrtf(ss * (1.0f / 128.0f) + 1e-5f);
  x0 *= rn;
  x1 *= rn;
  float y0 = x0 * cs - x1 * sn;
  float y1 = x0 * sn + x1 * cs;
  *p = (uint32_t)f2bf(y0) | ((uint32_t)f2bf(y1) << 16);
}

// Flash attention fwd (R18-verified, FROZEN): 8 waves/block, 256 q-rows/block
// (2 q-sets of 16/wave), KVBLK=64, triple-buffered K/V with counted vmcnt,
// fused Q RMSNorm+RoPE at load. GRID MUST BE 256 (qtile = gid>>5 in [0,8)).
__global__ __launch_bounds__(512, 1) void attn_k(const u16* __restrict__ qb,
                                                 const u16* __restrict__ kb,
                                                 const u16* __restrict__ vt,
                                                 const float* __restrict__ theta,
                                                 u16* __restrict__ yb) {
  __shared__ u16 sm[49152];  // K [3][64][128] @0, V [3][128][64] @24576 elems
  const int gid = blockIdx.x;
  const int bh = (gid & 7) * 4 + ((gid >> 3) & 3);
  const int qtile = gid >> 5;  // [0,8)
  const int b = bh >> 4, h = bh & 15;
  const int tid = threadIdx.x, lane = tid & 63, wid = tid >> 6;
  const int g = lane >> 4, lr = lane & 15;
  const int q0 = qtile * 256 + wid * 32;

  bf16x8 qf[2][4];
#pragma unroll
  for (int qs = 0; qs < 2; ++qs) {
    const int l = q0 + qs * 16 + lr;
    const u16* qrow = qb + (size_t)(bh * 2048 + l) * 128;
    float ss = 0.f;
#pragma unroll
    for (int ks = 0; ks < 4; ++ks) {
      bf16x8 raw = *(const bf16x8*)&qrow[ks * 32 + g * 8];
#pragma unroll
      for (int e = 0; e < 8; ++e) {
        float xv = bf2f((u16)raw[e]);
        ss += xv * xv;
      }
    }
    ss += __shfl_xor(ss, 16);
    ss += __shfl_xor(ss, 32);
    float rn = rsqrtf(ss * (1.0f / 128.0f) + 1e-5f) * 0.12751743f;  // *log2e/sqrt(128)
    const float* thp = theta + (size_t)(b * 2048 + l) * 1024 + h * 64;
#pragma unroll
    for (int ks = 0; ks < 4; ++ks) {
      bf16x8 raw = *(const bf16x8*)&qrow[ks * 32 + g * 8];
      float4 th4 = *(const float4*)&thp[ks * 16 + g * 4];
      union {
        uint32_t u[4];
        bf16x8 v;
      } outv;
#pragma unroll
      for (int j = 0; j < 4; ++j) {
        float th = (&th4.x)[j];
        float sn, cs;
        __sincosf(th, &sn, &cs);
        float x0 = bf2f((u16)raw[2 * j]) * rn;
        float x1 = bf2f((u16)raw[2 * j + 1]) * rn;
        outv.u[j] = pack2bf(x0 * cs - x1 * sn, x0 * sn + x1 * cs);
      }
      qf[qs][ks] = outv.v;
    }
  }

  auto stage = [&](int buf, int kv) {
#pragma unroll
    for (int i = 0; i < 2; ++i) {  // K tile 64x128
      int ci = i * 512 + tid;
      int row = ci >> 4, j = ci & 15;
      gl_lds16(kb + (size_t)(bh * 2048 + kv + row) * 128 + (j ^ (row & 7)) * 8,
               &sm[buf * 8192 + ci * 8]);
    }
#pragma unroll
    for (int i = 0; i < 2; ++i) {  // V tile 128x64
      int ci = i * 512 + tid;
      int row = ci >> 3, j = ci & 7;
      gl_lds16(vt + (size_t)(bh * 128 + row) * 2048 + kv + (j ^ (row & 7)) * 8,
               &sm[24576 + buf * 8192 + ci * 8]);
    }
  };

  f32x4 acc[2][8] = {};
  float mrun[2] = {-1e30f, -1e30f}, lrun[2] = {0.f, 0.f};
  const int sA = (2 * (g & 1)) * 16 + lr, sB = sA + 16;
  const bool hi2 = (g >> 1) != 0;

  stage(0, 0);
  stage(1, 64);
  asm volatile("s_waitcnt vmcnt(4)" ::: "memory");
  __builtin_amdgcn_s_barrier();

  int cur = 0;
  for (int t = 0; t < 32; ++t) {
    if (t < 31) {
      int nb = (cur == 0) ? 2 : cur - 1;           // (t+2)%3
      int kvn = ((t < 30) ? t + 2 : 31) * 64;
      stage(nb, kvn);
    }
    const u16* Ks = &sm[cur * 8192];
    const u16* Vs = &sm[24576 + cur * 8192];

    f32x4 st[2][4] = {};
#pragma unroll
    for (int ks = 0; ks < 4; ++ks) {
      bf16x8 kf[4];
#pragma unroll
      for (int kt = 0; kt < 4; ++kt) {
        int row = kt * 16 + lr;
        kf[kt] = *(const bf16x8*)&Ks[row * 128 + (((ks * 4 + g) ^ (row & 7)) * 8)];
      }
#pragma unroll
      for (int kt = 0; kt < 4; ++kt)
#pragma unroll
        for (int qs = 0; qs < 2; ++qs)
          st[qs][kt] =
              __builtin_amdgcn_mfma_f32_16x16x32_bf16(kf[kt], qf[qs][ks], st[qs][kt], 0, 0, 0);
    }

    float pmax[2];
#pragma unroll
    for (int qs = 0; qs < 2; ++qs) {
      float m01 = fmaxf(fmaxf(st[qs][0][0], st[qs][0][1]), fmaxf(st[qs][0][2], st[qs][0][3]));
      float m23 = fmaxf(fmaxf(st[qs][1][0], st[qs][1][1]), fmaxf(st[qs][1][2], st[qs][1][3]));
      float m45 = fmaxf(fmaxf(st[qs][2][0], st[qs][2][1]), fmaxf(st[qs][2][2], st[qs][2][3]));
      float m67 = fmaxf(fmaxf(st[qs][3][0], st[qs][3][1]), fmaxf(st[qs][3][2], st[qs][3][3]));
      float mx = fmaxf(fmaxf(m01, m23), fmaxf(m45, m67));
      mx = fmaxf(mx, __shfl_xor(mx, 16));
      mx = fmaxf(mx, __shfl_xor(mx, 32));
      pmax[qs] = mx;
    }
    float need = fmaxf(pmax[0] - mrun[0], pmax[1] - mrun[1]);
    if (!__all(need <= 8.0f)) {  // defer-max (T13)
#pragma unroll
      for (int qs = 0; qs < 2; ++qs) {
        float mnew = fmaxf(mrun[qs], pmax[qs]);
        float corr = __builtin_amdgcn_exp2f(mrun[qs] - mnew);
        lrun[qs] *= corr;
        mrun[qs] = mnew;
#pragma unroll
        for (int ct = 0; ct < 8; ++ct) {
          acc[qs][ct][0] *= corr;
          acc[qs][ct][1] *= corr;
          acc[qs][ct][2] *= corr;
          acc[qs][ct][3] *= corr;
        }
      }
    }
    uint32_t pw[2][4][2];
#pragma unroll
    for (int qs = 0; qs < 2; ++qs) {
      float rsum = 0.f;
#pragma unroll
      for (int kt = 0; kt < 4; ++kt)
#pragma unroll
        for (int hf = 0; hf < 2; ++hf) {
          float e0 = __builtin_amdgcn_exp2f(st[qs][kt][2 * hf] - mrun[qs]);
          float e1 = __builtin_amdgcn_exp2f(st[qs][kt][2 * hf + 1] - mrun[qs]);
          rsum += e0 + e1;
          pw[qs][kt][hf] = pack2bf(e0, e1);
        }
      rsum += __shfl_xor(rsum, 16);
      rsum += __shfl_xor(rsum, 32);
      lrun[qs] += rsum;
    }

#pragma unroll
    for (int ks2 = 0; ks2 < 2; ++ks2) {
      bf16x8 pf[2];
#pragma unroll
      for (int qs = 0; qs < 2; ++qs) {
        uint32_t a0 = __shfl(pw[qs][ks2 * 2][0], sA);
        uint32_t a1 = __shfl(pw[qs][ks2 * 2][1], sA);
        uint32_t a2 = __shfl(pw[qs][ks2 * 2][0], sB);
        uint32_t a3 = __shfl(pw[qs][ks2 * 2][1], sB);
        uint32_t b0 = __shfl(pw[qs][ks2 * 2 + 1][0], sA);
        uint32_t b1 = __shfl(pw[qs][ks2 * 2 + 1][1], sA);
        uint32_t b2 = __shfl(pw[qs][ks2 * 2 + 1][0], sB);
        uint32_t b3 = __shfl(pw[qs][ks2 * 2 + 1][1], sB);
        union {
          uint32_t u[4];
          bf16x8 v;
        } tt;
        tt.u[0] = hi2 ? b0 : a0;
        tt.u[1] = hi2 ? b1 : a1;
        tt.u[2] = hi2 ? b2 : a2;
        tt.u[3] = hi2 ? b3 : a3;
        pf[qs] = tt.v;
      }
#pragma unroll
      for (int ct = 0; ct < 8; ++ct) {
        int row = ct * 16 + lr;
        bf16x8 vf = *(const bf16x8*)&Vs[row * 64 + (((ks2 * 4 + g) ^ (row & 7)) * 8)];
#pragma unroll
        for (int qs = 0; qs < 2; ++qs)
          acc[qs][ct] = __builtin_amdgcn_mfma_f32_16x16x32_bf16(vf, pf[qs], acc[qs][ct], 0, 0, 0);
      }
    }
    if (t < 31) {
      asm volatile("s_waitcnt vmcnt(4)" ::: "memory");
      __builtin_amdgcn_s_barrier();
    }
    cur = (cur == 2) ? 0 : cur + 1;
  }
  asm volatile("s_waitcnt vmcnt(0)" ::: "memory");

#pragma unroll
  for (int qs = 0; qs < 2; ++qs) {
    float inv = 1.f / lrun[qs];
    const size_t orow = (size_t)(b * 2048 + q0 + qs * 16 + lr) * 2048 + h * 128;
#pragma unroll
    for (int ct = 0; ct < 8; ++ct) {
      uint32_t lo = pack2bf(acc[qs][ct][0] * inv, acc[qs][ct][1] * inv);
      uint32_t hi = pack2bf(acc[qs][ct][2] * inv, acc[qs][ct][3] * inv);
      *(uint2*)&yb[orow + ct * 16 + g * 4] = make_uint2(lo, hi);
    }
  }
}

extern "C" void kernel_launch(void* const* d_in, const int* in_sizes, int n_in,
                              void* d_out, int out_size, void* d_ws, size_t ws_size,
                              hipStream_t stream) {
  const float* x = (const float*)d_in[0];
  const float* theta = (const float*)d_in[1];
  const float* wqkv = (const float*)d_in[2];
  const float* wy = (const float*)d_in[3];
  const float* by = (const float*)d_in[4];
  float* out = (float*)d_out;
  char* ws = (char*)d_ws;
  u16* xb  = (u16*)(ws + 0);
  u16* wqb = (u16*)(ws + 16777216);
  u16* wyb = (u16*)(ws + 41943040);
  u16* qb  = (u16*)(ws + 50331648);
  u16* kb  = (u16*)(ws + 67108864);
  u16* vt  = (u16*)(ws + 83886080);
  u16* yb  = (u16*)(ws + 100663296);

  cast3<<<2048, 256, 0, stream>>>(x, wqkv, wy, xb, wqb, wyb);
  gemm8_qkv<<<dim3(32, 16), 512, 0, stream>>>(xb, wqb, qb, kb, vt);
  k_fix<<<16384, 256, 0, stream>>>(kb, theta);
  attn_k<<<256, 512, 0, stream>>>(qb, kb, vt, theta, yb);
  gemm_out<<<dim3(16, 32), 256, 0, stream>>>(yb, wyb, out, by);
}